// Round 3
// baseline (1265.964 us; speedup 1.0000x reference)
//
#include <hip/hip_runtime.h>

// B=16384, N=54, D_IN=64, D_HID=4, D_OUT=256
// Barrier-free fused kernel.
//
// Block = 256 threads = 4 waves. Wave w owns 4 batch rows (one per 16-lane
// group). Inner loop walks board columns n=0..53. Per step each group computes
// its row's 4 hidden values (7 coalesced float4 loads, dot vs LDS weights,
// 16-lane xor-butterfly -> every lane holds h[0..3]); h is broadcast across
// groups with uniform-lane __shfl (no LDS, no barrier). Each lane owns 4
// output columns (col = 64j + lane) and accumulates acc2[4][4] in registers;
// Wf is read straight from L2 (221 KB, resident), batched per column-pair for
// 32B line contiguity. Single barrier total (weight staging).

#define N_POS   54
#define D_OUT   256
#define THREADS 256
#define RB      16          // rows per block = 4 waves * 4 rows

__global__ __launch_bounds__(THREADS, 4)
void hexconv_fc_kernel(const float* __restrict__ x,
                       const float* __restrict__ nb,
                       const float* __restrict__ Wc,
                       const float* __restrict__ bc,
                       const float* __restrict__ Wd,
                       const float* __restrict__ bd,
                       const float* __restrict__ Wf,
                       const float* __restrict__ bf,
                       float* __restrict__ out)
{
    // combined weights: wlds4[hh*112 + f], f = t + 16*j ; j=0 -> Wc, j>=1 -> Wd[j-1]
    __shared__ float4 wlds4[4 * 112];   // 7168 B

    const int tid  = threadIdx.x;
    const int wv   = tid >> 6;          // wave 0..3
    const int lane = tid & 63;
    const int g    = lane >> 4;         // group (row) 0..3
    const int t    = lane & 15;         // lane in group

    // ---- stage combined weights into LDS ----
    const float4* Wc4 = (const float4*)Wc;   // [4][16]
    const float4* Wd4 = (const float4*)Wd;   // [6][4][16]
    for (int idx = tid; idx < 4 * 112; idx += THREADS) {
        const int hh = idx / 112;
        const int f  = idx - hh * 112;
        float4 v;
        if (f < 16) {
            v = Wc4[hh * 16 + f];
        } else {
            const int k  = (f - 16) >> 4;
            const int d4 = (f - 16) & 15;
            v = Wd4[(k * 4 + hh) * 16 + d4];
        }
        wlds4[idx] = v;
    }

    // ---- bias: bc[hh] + sum_k bd[k][hh] ----
    float bias[4];
#pragma unroll
    for (int hh = 0; hh < 4; ++hh) {
        float s = bc[hh];
#pragma unroll
        for (int k = 0; k < 6; ++k) s += bd[k * 4 + hh];
        bias[hh] = s;
    }

    const int b0     = blockIdx.x * RB;
    const int myRow  = b0 + wv * 4 + g;         // hexconv row this lane works on
    const int posBase = myRow * N_POS;

    const float4* x4  = (const float4*)x;    // [pos][16]
    const float4* nb4 = (const float4*)nb;   // [pos][96]
    const float4* Wf4 = (const float4*)Wf;   // [256][54]

    float acc2[4][4];                        // [g2 (row)][j (col chunk)]
#pragma unroll
    for (int a = 0; a < 4; ++a)
#pragma unroll
        for (int b = 0; b < 4; ++b) acc2[a][b] = 0.f;

    __syncthreads();                         // the only barrier

    for (int s = 0; s < N_POS / 2; ++s) {
        // Wf for columns n=2s, 2s+1: per lane, its 4 output cols (64j+lane)
        float4 wfe[4], wfo[4];
#pragma unroll
        for (int j = 0; j < 4; ++j) {
            const int base = (64 * j + lane) * 54 + 2 * s;
            wfe[j] = Wf4[base];
            wfo[j] = Wf4[base + 1];
        }

#pragma unroll
        for (int half = 0; half < 2; ++half) {
            const int n = 2 * s + half;
            const int posIdx = posBase + n;

            float4 data[7];
            data[0] = x4[posIdx * 16 + t];
#pragma unroll
            for (int j = 1; j < 7; ++j)
                data[j] = nb4[posIdx * 96 + (t + 16 * (j - 1))];

            float acc[4] = {0.f, 0.f, 0.f, 0.f};
#pragma unroll
            for (int j = 0; j < 7; ++j) {
                const float4 d = data[j];
#pragma unroll
                for (int hh = 0; hh < 4; ++hh) {
                    const float4 w = wlds4[hh * 112 + t + 16 * j];
                    acc[hh] += d.x * w.x + d.y * w.y + d.z * w.z + d.w * w.w;
                }
            }

            // 16-lane xor-butterfly: every lane of the group gets full sums
#pragma unroll
            for (int hh = 0; hh < 4; ++hh) {
#pragma unroll
                for (int m = 1; m <= 8; m <<= 1)
                    acc[hh] += __shfl_xor(acc[hh], m, 64);
            }

            float hval[4];
#pragma unroll
            for (int hh = 0; hh < 4; ++hh) {
                const float v = acc[hh] + bias[hh];
                hval[hh] = v > 0.f ? v : 0.f;
            }

            // broadcast each group's h across the wave, accumulate FC
#pragma unroll
            for (int g2 = 0; g2 < 4; ++g2) {
                float hb[4];
#pragma unroll
                for (int hh = 0; hh < 4; ++hh)
                    hb[hh] = __shfl(hval[hh], g2 * 16, 64);
#pragma unroll
                for (int j = 0; j < 4; ++j) {
                    const float4 w = (half == 0) ? wfe[j] : wfo[j];
                    acc2[g2][j] += hb[0] * w.x + hb[1] * w.y
                                 + hb[2] * w.z + hb[3] * w.w;
                }
            }
        }
    }

    // ---- store: lane covers 4 rows x 4 cols, coalesced over lane ----
#pragma unroll
    for (int j = 0; j < 4; ++j) {
        const int col = 64 * j + lane;
        const float bfv = bf[col];
#pragma unroll
        for (int g2 = 0; g2 < 4; ++g2)
            out[(b0 + wv * 4 + g2) * D_OUT + col] = acc2[g2][j] + bfv;
    }
}

extern "C" void kernel_launch(void* const* d_in, const int* in_sizes, int n_in,
                              void* d_out, int out_size, void* d_ws, size_t ws_size,
                              hipStream_t stream) {
    const float* x  = (const float*)d_in[0];
    const float* nb = (const float*)d_in[1];
    const float* Wc = (const float*)d_in[2];
    const float* bc = (const float*)d_in[3];
    const float* Wd = (const float*)d_in[4];
    const float* bd = (const float*)d_in[5];
    const float* Wf = (const float*)d_in[6];
    const float* bf = (const float*)d_in[7];
    float* out = (float*)d_out;

    const int B = 16384;
    dim3 grid(B / RB), block(THREADS);
    hexconv_fc_kernel<<<grid, block, 0, stream>>>(x, nb, Wc, bc, Wd, bd, Wf, bf, out);
}

// Round 4
// 402.646 us; speedup vs baseline: 3.1441x; 3.1441x over previous
//
#include <hip/hip_runtime.h>

// B=16384, N=54, D_IN=64, D_HID=4, D_OUT=256
// Barrier-free fused kernel, register-disciplined (R3 spilled: launch_bounds
// min-waves attr forced 64 VGPRs -> 1.7 GB scratch writes).
//
// Block = 256 threads = 4 waves; wave owns 4 batch rows (one per 16-lane
// group). Per column n: each group computes its row's h[0..4] (7 coalesced
// float4 loads, dot vs LDS weights, 16-lane xor-butterfly), h broadcast
// across groups via uniform-lane __shfl (readlane), FC accumulated into 16
// named registers (lane owns cols {lane,64+lane,128+lane,192+lane} x 4 rows).
// Wf float4s loaded just-in-time per column from L2 (221 KB resident).
// Single barrier total (weight staging). All hot state in named scalars.

#define N_POS   54
#define D_OUT   256
#define THREADS 256
#define RB      16

__global__ __launch_bounds__(THREADS)
void hexconv_fc_kernel(const float* __restrict__ x,
                       const float* __restrict__ nb,
                       const float* __restrict__ Wc,
                       const float* __restrict__ bc,
                       const float* __restrict__ Wd,
                       const float* __restrict__ bd,
                       const float* __restrict__ Wf,
                       const float* __restrict__ bf,
                       float* __restrict__ out)
{
    // combined weights: wlds4[hh*112 + t + 16*j]; j=0 -> Wc, j>=1 -> Wd[j-1]
    __shared__ float4 wlds4[4 * 112];   // 7168 B

    const int tid  = threadIdx.x;
    const int wv   = tid >> 6;          // wave 0..3
    const int lane = tid & 63;
    const int g    = lane >> 4;         // group (row) 0..3
    const int t    = lane & 15;         // lane in group

    const float4* Wc4 = (const float4*)Wc;   // [4][16]
    const float4* Wd4 = (const float4*)Wd;   // [6][4][16]
    for (int idx = tid; idx < 4 * 112; idx += THREADS) {
        const int hh = idx / 112;
        const int f  = idx - hh * 112;
        float4 v;
        if (f < 16) {
            v = Wc4[hh * 16 + f];
        } else {
            const int k  = (f - 16) >> 4;
            const int d4 = (f - 16) & 15;
            v = Wd4[(k * 4 + hh) * 16 + d4];
        }
        wlds4[idx] = v;
    }

    // bias (lane-uniform -> SGPRs)
    float bias0 = bc[0], bias1 = bc[1], bias2 = bc[2], bias3 = bc[3];
#pragma unroll
    for (int k = 0; k < 6; ++k) {
        bias0 += bd[k * 4 + 0];
        bias1 += bd[k * 4 + 1];
        bias2 += bd[k * 4 + 2];
        bias3 += bd[k * 4 + 3];
    }

    const int b0 = blockIdx.x * RB;
    const size_t posBase = (size_t)(b0 + wv * 4 + g) * N_POS;

    const float4* x4  = (const float4*)x;    // [pos][16]
    const float4* nb4 = (const float4*)nb;   // [pos][96]
    const float4* Wf4 = (const float4*)Wf;   // [256][54]

    // FC accumulators: A{row g2}{col chunk j}, all named scalars
    float A00=0.f,A01=0.f,A02=0.f,A03=0.f;
    float A10=0.f,A11=0.f,A12=0.f,A13=0.f;
    float A20=0.f,A21=0.f,A22=0.f,A23=0.f;
    float A30=0.f,A31=0.f,A32=0.f,A33=0.f;

    __syncthreads();                         // the only barrier

    for (int n = 0; n < N_POS; ++n) {
        const size_t p = posBase + n;
        const float4* xp  = x4  + p * 16 + t;
        const float4* nbp = nb4 + p * 96 + t;

        const float4 d0 = xp[0];
        const float4 d1 = nbp[0];
        const float4 d2 = nbp[16];
        const float4 d3 = nbp[32];
        const float4 d4 = nbp[48];
        const float4 d5 = nbp[64];
        const float4 d6 = nbp[80];

        float a0 = 0.f, a1 = 0.f, a2 = 0.f, a3 = 0.f;
#define HEX(D, J) do {                                                         \
        float4 w_;                                                             \
        w_ = wlds4[0*112 + t + 16*(J)];                                        \
        a0 += (D).x*w_.x + (D).y*w_.y + (D).z*w_.z + (D).w*w_.w;               \
        w_ = wlds4[1*112 + t + 16*(J)];                                        \
        a1 += (D).x*w_.x + (D).y*w_.y + (D).z*w_.z + (D).w*w_.w;               \
        w_ = wlds4[2*112 + t + 16*(J)];                                        \
        a2 += (D).x*w_.x + (D).y*w_.y + (D).z*w_.z + (D).w*w_.w;               \
        w_ = wlds4[3*112 + t + 16*(J)];                                        \
        a3 += (D).x*w_.x + (D).y*w_.y + (D).z*w_.z + (D).w*w_.w;               \
    } while (0)
        HEX(d0, 0); HEX(d1, 1); HEX(d2, 2); HEX(d3, 3);
        HEX(d4, 4); HEX(d5, 5); HEX(d6, 6);
#undef HEX

        // 16-lane xor-butterfly: all lanes of a group get the full sums
#pragma unroll
        for (int m = 1; m <= 8; m <<= 1) {
            a0 += __shfl_xor(a0, m, 64);
            a1 += __shfl_xor(a1, m, 64);
            a2 += __shfl_xor(a2, m, 64);
            a3 += __shfl_xor(a3, m, 64);
        }

        const float h0 = fmaxf(a0 + bias0, 0.f);
        const float h1 = fmaxf(a1 + bias1, 0.f);
        const float h2 = fmaxf(a2 + bias2, 0.f);
        const float h3 = fmaxf(a3 + bias3, 0.f);

        // Wf for column n, this lane's 4 output cols (JIT, L2-resident)
        const float4 wf0 = Wf4[(size_t)(      lane) * 54 + n];
        const float4 wf1 = Wf4[(size_t)( 64 + lane) * 54 + n];
        const float4 wf2 = Wf4[(size_t)(128 + lane) * 54 + n];
        const float4 wf3 = Wf4[(size_t)(192 + lane) * 54 + n];

        // broadcast each group's h (uniform src lane -> readlane) and accumulate
#define FC(G2, AW, AX, AY, AZ) do {                                            \
        const float hb0 = __shfl(h0, (G2) * 16, 64);                           \
        const float hb1 = __shfl(h1, (G2) * 16, 64);                           \
        const float hb2 = __shfl(h2, (G2) * 16, 64);                           \
        const float hb3 = __shfl(h3, (G2) * 16, 64);                           \
        AW += hb0*wf0.x + hb1*wf0.y + hb2*wf0.z + hb3*wf0.w;                   \
        AX += hb0*wf1.x + hb1*wf1.y + hb2*wf1.z + hb3*wf1.w;                   \
        AY += hb0*wf2.x + hb1*wf2.y + hb2*wf2.z + hb3*wf2.w;                   \
        AZ += hb0*wf3.x + hb1*wf3.y + hb2*wf3.z + hb3*wf3.w;                   \
    } while (0)
        FC(0, A00, A01, A02, A03);
        FC(1, A10, A11, A12, A13);
        FC(2, A20, A21, A22, A23);
        FC(3, A30, A31, A32, A33);
#undef FC
    }

    // store: lane covers 4 rows x 4 cols, coalesced over lane
    const float bf0 = bf[lane];
    const float bf1 = bf[64 + lane];
    const float bf2 = bf[128 + lane];
    const float bf3 = bf[192 + lane];

#define ST(G2, AW, AX, AY, AZ) do {                                            \
        float* o_ = out + (size_t)(b0 + wv * 4 + (G2)) * D_OUT + lane;         \
        o_[0]   = AW + bf0;                                                    \
        o_[64]  = AX + bf1;                                                    \
        o_[128] = AY + bf2;                                                    \
        o_[192] = AZ + bf3;                                                    \
    } while (0)
    ST(0, A00, A01, A02, A03);
    ST(1, A10, A11, A12, A13);
    ST(2, A20, A21, A22, A23);
    ST(3, A30, A31, A32, A33);
#undef ST
}

extern "C" void kernel_launch(void* const* d_in, const int* in_sizes, int n_in,
                              void* d_out, int out_size, void* d_ws, size_t ws_size,
                              hipStream_t stream) {
    const float* x  = (const float*)d_in[0];
    const float* nb = (const float*)d_in[1];
    const float* Wc = (const float*)d_in[2];
    const float* bc = (const float*)d_in[3];
    const float* Wd = (const float*)d_in[4];
    const float* bd = (const float*)d_in[5];
    const float* Wf = (const float*)d_in[6];
    const float* bf = (const float*)d_in[7];
    float* out = (float*)d_out;

    const int B = 16384;
    dim3 grid(B / RB), block(THREADS);
    hexconv_fc_kernel<<<grid, block, 0, stream>>>(x, nb, Wc, bc, Wd, bd, Wf, bf, out);
}